// Round 16
// baseline (163.728 us; speedup 1.0000x reference)
//
#include <hip/hip_runtime.h>

typedef __bf16 bf16_t;
typedef bf16_t bf16x8 __attribute__((ext_vector_type(8)));
typedef unsigned short u16x8 __attribute__((ext_vector_type(8)));
typedef float f32x4 __attribute__((ext_vector_type(4)));
typedef _Float16 f16x8 __attribute__((ext_vector_type(8)));

union BF8 { u16x8 u; bf16x8 b; };

__device__ __forceinline__ unsigned short f2bf(float f) {
  unsigned int u = __float_as_uint(f);
  unsigned int r = (u + 0x7FFFu + ((u >> 16) & 1u)) >> 16;
  return (unsigned short)r;
}
__device__ __forceinline__ float bf2f(unsigned short s) {
  return __uint_as_float(((unsigned int)s) << 16);
}

// ---------------- prep: weights -> MFMA-frag-ready bf16 layouts --------------
__global__ __launch_bounds__(256) void kprep(const float* __restrict__ W1,
                                             const float* __restrict__ W2,
                                             const float* __restrict__ W,
                                             unsigned short* __restrict__ Wfh,
                                             unsigned short* __restrict__ Wfl,
                                             unsigned short* __restrict__ W2h,
                                             unsigned short* __restrict__ W2l,
                                             unsigned short* __restrict__ Wfb) {
  int idx = blockIdx.x * 256 + threadIdx.x;
  if (idx < 204800) {
    int e = idx & 7, lane = (idx >> 3) & 63, nt = (idx >> 9) & 15, ks = idx >> 13;
    int k = ks * 32 + (lane >> 4) * 8 + e;
    int col = nt * 16 + (lane & 15);
    int a = col >> 6, o = col & 63;
    float v = (k < 784) ? W1[(a * 784 + k) * 64 + o] : 0.f;
    unsigned short hi = f2bf(v);
    Wfh[idx] = hi;
    Wfl[idx] = f2bf(v - bf2f(hi));
  }
  if (idx < 16384) {
    int a = idx >> 12, o = (idx >> 6) & 63, k = idx & 63;
    float v = W2[(a * 64 + k) * 64 + o];
    unsigned short hi = f2bf(v);
    W2h[idx] = hi;
    W2l[idx] = f2bf(v - bf2f(hi));
  }
  if (idx < 81920) {
    int e = idx & 7;
    int t = idx >> 3;
    int lane = t & 63; t >>= 6;
    int kc = t & 1;   t >>= 1;
    int nt = t % 20;
    int a  = t / 20;
    int row = nt * 16 + (lane & 15);
    int kk  = kc * 32 + (lane >> 4) * 8 + e;
    Wfb[idx] = f2bf(W[(a * 320 + row) * 64 + kk]);
  }
}

// ---------------- kA: h = relu(x@W1 + b1), split-bf16, -> packed u32 ---------
// (unchanged from R9) 512 threads, BM=64, x double-buffered, W frags direct.
__global__ __launch_bounds__(512, 4) void kA(const float* __restrict__ x,
                                             const float* __restrict__ b1,
                                             const unsigned short* __restrict__ Wfh,
                                             const unsigned short* __restrict__ Wfl,
                                             unsigned int* __restrict__ H) {
  __shared__ unsigned short xsh[2][64 * 40];
  __shared__ unsigned short xsl[2][64 * 40];
  __shared__ float b1s[256];
  const int tid = threadIdx.x;
  const int w   = tid >> 6;
  const int l   = tid & 63;
  const int l15 = l & 15;
  const int lg4 = l >> 4;
  const int k8  = lg4 * 8;
  const int b0  = blockIdx.x * 64;

  if (tid < 256) b1s[tid] = b1[tid];

  const f32x4 fz = {0.f, 0.f, 0.f, 0.f};
  f32x4 acc[4][2];
#pragma unroll
  for (int mt = 0; mt < 4; ++mt)
#pragma unroll
    for (int n = 0; n < 2; ++n) acc[mt][n] = fz;

  const int srow = tid >> 3;
  const int skq  = (tid & 7) * 4;
  const float* xrow = x + (size_t)(b0 + srow) * 784;

  {
    f32x4 xv = fz;
    if (skq < 784) xv = *(const f32x4*)(xrow + skq);
    unsigned int ph[2], pl[2];
#pragma unroll
    for (int j = 0; j < 2; ++j) {
      unsigned short h0 = f2bf(xv[2 * j]), h1 = f2bf(xv[2 * j + 1]);
      unsigned short s0 = f2bf(xv[2 * j] - bf2f(h0));
      unsigned short s1 = f2bf(xv[2 * j + 1] - bf2f(h1));
      ph[j] = (unsigned int)h0 | ((unsigned int)h1 << 16);
      pl[j] = (unsigned int)s0 | ((unsigned int)s1 << 16);
    }
    *(uint2*)&xsh[0][srow * 40 + skq] = *(uint2*)ph;
    *(uint2*)&xsl[0][srow * 40 + skq] = *(uint2*)pl;
  }

  for (int ks = 0; ks < 25; ++ks) {
    const int cur = ks & 1;
    f32x4 xn = fz;
    if (ks < 24) {
      int kf = (ks + 1) * 32 + skq;
      if (kf < 784) xn = *(const f32x4*)(xrow + kf);
    }
    __syncthreads();

    const int nt0 = w * 2;
    bf16x8 bh0 = *(const bf16x8*)(Wfh + ((size_t)(ks * 16 + nt0) * 64 + l) * 8);
    bf16x8 bl0 = *(const bf16x8*)(Wfl + ((size_t)(ks * 16 + nt0) * 64 + l) * 8);
    bf16x8 bh1 = *(const bf16x8*)(Wfh + ((size_t)(ks * 16 + nt0 + 1) * 64 + l) * 8);
    bf16x8 bl1 = *(const bf16x8*)(Wfl + ((size_t)(ks * 16 + nt0 + 1) * 64 + l) * 8);

    bf16x8 ah[4], al[4];
#pragma unroll
    for (int mt = 0; mt < 4; ++mt) {
      ah[mt] = *(const bf16x8*)&xsh[cur][(mt * 16 + l15) * 40 + k8];
      al[mt] = *(const bf16x8*)&xsl[cur][(mt * 16 + l15) * 40 + k8];
    }

#pragma unroll
    for (int mt = 0; mt < 4; ++mt) {
      acc[mt][0] = __builtin_amdgcn_mfma_f32_16x16x32_bf16(ah[mt], bh0, acc[mt][0], 0, 0, 0);
      acc[mt][0] = __builtin_amdgcn_mfma_f32_16x16x32_bf16(al[mt], bh0, acc[mt][0], 0, 0, 0);
      acc[mt][0] = __builtin_amdgcn_mfma_f32_16x16x32_bf16(ah[mt], bl0, acc[mt][0], 0, 0, 0);
      acc[mt][1] = __builtin_amdgcn_mfma_f32_16x16x32_bf16(ah[mt], bh1, acc[mt][1], 0, 0, 0);
      acc[mt][1] = __builtin_amdgcn_mfma_f32_16x16x32_bf16(al[mt], bh1, acc[mt][1], 0, 0, 0);
      acc[mt][1] = __builtin_amdgcn_mfma_f32_16x16x32_bf16(ah[mt], bl1, acc[mt][1], 0, 0, 0);
    }

    if (ks < 24) {
      unsigned int ph[2], pl[2];
#pragma unroll
      for (int j = 0; j < 2; ++j) {
        unsigned short h0 = f2bf(xn[2 * j]), h1 = f2bf(xn[2 * j + 1]);
        unsigned short s0 = f2bf(xn[2 * j] - bf2f(h0));
        unsigned short s1 = f2bf(xn[2 * j + 1] - bf2f(h1));
        ph[j] = (unsigned int)h0 | ((unsigned int)h1 << 16);
        pl[j] = (unsigned int)s0 | ((unsigned int)s1 << 16);
      }
      *(uint2*)&xsh[cur ^ 1][srow * 40 + skq] = *(uint2*)ph;
      *(uint2*)&xsl[cur ^ 1][srow * 40 + skq] = *(uint2*)pl;
    }
  }

#pragma unroll
  for (int mt = 0; mt < 4; ++mt)
#pragma unroll
    for (int n = 0; n < 2; ++n) {
      int col = (w * 2 + n) * 16 + l15;
      float bb = b1s[col];
#pragma unroll
      for (int r = 0; r < 4; ++r) {
        int row = b0 + mt * 16 + lg4 * 4 + r;
        float v = acc[mt][n][r] + bb;
        v = v > 0.f ? v : 0.f;
        unsigned short hi = f2bf(v);
        unsigned short lo = f2bf(v - bf2f(hi));
        H[(size_t)row * 256 + col] = (unsigned int)hi | ((unsigned int)lo << 16);
      }
    }
}

// ---------------- kB1: GEMM2 + squash + u_hat -> UH (fp16, dump layout) ------
// 16 samples/block (grid 2048), R9's proven phases 1-2; u_hat computed one
// nt at a time (small regs), stored as UH[blk][a][nt][lg4][r][l15] fp16.
__global__ __launch_bounds__(256, 4) void kB1(const unsigned int* __restrict__ H,
                                              const float* __restrict__ b2,
                                              const unsigned short* __restrict__ W2h,
                                              const unsigned short* __restrict__ W2l,
                                              const unsigned short* __restrict__ Wfb,
                                              _Float16* __restrict__ UH) {
  __shared__ float smem[4352];  // u_scr only (R9 layout, stride 68)
  const int tid = threadIdx.x;
  const int a   = tid >> 6;   // wave = agent
  const int l   = tid & 63;
  const int l15 = l & 15;
  const int lg4 = l >> 4;
  const int k8  = lg4 * 8;
  const int b0  = blockIdx.x * 16;
  const f32x4 fz = {0.f, 0.f, 0.f, 0.f};

  // ---- phase 1: GEMM2 (split-bf16) + b2 + squash -> u (f32 in u_scr)
  bf16x8 hh[2], hl[2];
#pragma unroll
  for (int kc = 0; kc < 2; ++kc) {
    const uint4* hp = (const uint4*)(H + (size_t)(b0 + l15) * 256 + a * 64 + kc * 32 + k8);
    uint4 q0 = hp[0], q1 = hp[1];
    unsigned int pw[8] = {q0.x, q0.y, q0.z, q0.w, q1.x, q1.y, q1.z, q1.w};
    BF8 vh, vl;
#pragma unroll
    for (int j = 0; j < 8; ++j) {
      vh.u[j] = (unsigned short)(pw[j] & 0xFFFFu);
      vl.u[j] = (unsigned short)(pw[j] >> 16);
    }
    hh[kc] = vh.b;
    hl[kc] = vl.b;
  }
  f32x4 a2[4];
#pragma unroll
  for (int ot = 0; ot < 4; ++ot) a2[ot] = fz;
#pragma unroll
  for (int ot = 0; ot < 4; ++ot)
#pragma unroll
    for (int kc = 0; kc < 2; ++kc) {
      bf16x8 bh = *(const bf16x8*)(W2h + ((a * 64 + ot * 16 + l15) * 64 + kc * 32 + k8));
      bf16x8 bl = *(const bf16x8*)(W2l + ((a * 64 + ot * 16 + l15) * 64 + kc * 32 + k8));
      a2[ot] = __builtin_amdgcn_mfma_f32_16x16x32_bf16(hh[kc], bh, a2[ot], 0, 0, 0);
      a2[ot] = __builtin_amdgcn_mfma_f32_16x16x32_bf16(hl[kc], bh, a2[ot], 0, 0, 0);
      a2[ot] = __builtin_amdgcn_mfma_f32_16x16x32_bf16(hh[kc], bl, a2[ot], 0, 0, 0);
    }
  float b2v[4];
#pragma unroll
  for (int ot = 0; ot < 4; ++ot) b2v[ot] = b2[a * 64 + ot * 16 + l15];
#pragma unroll
  for (int r = 0; r < 4; ++r) {
    float up[4];
    float sq = 0.f;
#pragma unroll
    for (int ot = 0; ot < 4; ++ot) {
      float v = a2[ot][r] + b2v[ot];
      up[ot] = v;
      sq += v * v;
    }
    sq += __shfl_xor(sq, 1, 64);
    sq += __shfl_xor(sq, 2, 64);
    sq += __shfl_xor(sq, 4, 64);
    sq += __shfl_xor(sq, 8, 64);
    float scale = sq / ((1.f + sq) * sqrtf(sq + 1e-8f));
#pragma unroll
    for (int ot = 0; ot < 4; ++ot)
      smem[a * 1088 + (lg4 * 4 + r) * 68 + ot * 16 + l15] = scale * up[ot];
  }
  __syncthreads();

  // ---- phase 2: u A-frags (transpose read, split hi/lo)
  bf16x8 uah[2], ual[2];
#pragma unroll
  for (int kc = 0; kc < 2; ++kc) {
    float4 f0 = *(const float4*)&smem[a * 1088 + l15 * 68 + kc * 32 + k8];
    float4 f1 = *(const float4*)&smem[a * 1088 + l15 * 68 + kc * 32 + k8 + 4];
    float vv[8] = {f0.x, f0.y, f0.z, f0.w, f1.x, f1.y, f1.z, f1.w};
    BF8 vh, vl;
#pragma unroll
    for (int j = 0; j < 8; ++j) {
      unsigned short hi = f2bf(vv[j]);
      vh.u[j] = hi;
      vl.u[j] = f2bf(vv[j] - bf2f(hi));
    }
    uah[kc] = vh.b;
    ual[kc] = vl.b;
  }

  // ---- phase 3: u_hat MFMA one nt at a time -> UH fp16 (dump layout)
#pragma unroll
  for (int nt = 0; nt < 20; ++nt) {
    f32x4 au = fz;
#pragma unroll
    for (int kc = 0; kc < 2; ++kc) {
      bf16x8 bh = *(const bf16x8*)(Wfb + ((size_t)((a * 20 + nt) * 2 + kc) * 64 + l) * 8);
      au = __builtin_amdgcn_mfma_f32_16x16x32_bf16(uah[kc], bh, au, 0, 0, 0);
      au = __builtin_amdgcn_mfma_f32_16x16x32_bf16(ual[kc], bh, au, 0, 0, 0);
    }
    size_t base = ((((size_t)blockIdx.x * 4 + a) * 20 + nt) * 4 + lg4) * 4;
#pragma unroll
    for (int r = 0; r < 4; ++r)
      UH[(base + r) * 16 + l15] = (_Float16)au[r];
  }
}

// ---------------- kB2: Gram + routing + v from UH (no LDS, no barriers) ------
// 8 threads/sample: (gjl = j parity, gih = i quarter). 32 samples/block.
__global__ __launch_bounds__(256, 4) void kB2(const _Float16* __restrict__ UH,
                                              float* __restrict__ out) {
  const int tid  = threadIdx.x;
  const int gjl  = (tid >> 2) & 1;
  const int gih  = tid & 3;
  const int s    = blockIdx.x * 32 + (tid >> 3);
  const int blk  = s >> 4, l4 = (s >> 2) & 3, rr = s & 3;
  const size_t base0 = (size_t)blk * 20480 + l4 * 64 + rr * 16 + (gih & 1) * 8;
  const int ihh  = gih >> 1;

  float Gj[5][10];
#pragma unroll
  for (int rd = 0; rd < 5; ++rd)
#pragma unroll
    for (int p = 0; p < 10; ++p) Gj[rd][p] = 0.f;

  // ---- Gram pass: 8 i-values per thread per (rd, aa)
#pragma unroll
  for (int rd = 0; rd < 5; ++rd) {
    const int nt = 2 * (2 * rd + gjl) + ihh;
    float f[4][8];
#pragma unroll
    for (int aa = 0; aa < 4; ++aa) {
      f16x8 v = *(const f16x8*)(UH + base0 + (size_t)aa * 5120 + nt * 256);
#pragma unroll
      for (int e = 0; e < 8; ++e) f[aa][e] = (float)v[e];
    }
#pragma unroll
    for (int e = 0; e < 8; ++e) {
      float v0 = f[0][e], v1 = f[1][e], v2 = f[2][e], v3 = f[3][e];
      Gj[rd][0] += v0 * v0; Gj[rd][1] += v0 * v1; Gj[rd][2] += v0 * v2; Gj[rd][3] += v0 * v3;
      Gj[rd][4] += v1 * v1; Gj[rd][5] += v1 * v2; Gj[rd][6] += v1 * v3;
      Gj[rd][7] += v2 * v2; Gj[rd][8] += v2 * v3;
      Gj[rd][9] += v3 * v3;
    }
  }
  // combine i-quarters (lanes xor 1, 2 within the 4-lane gih group)
#pragma unroll
  for (int rd = 0; rd < 5; ++rd)
#pragma unroll
    for (int p = 0; p < 10; ++p) {
      Gj[rd][p] += __shfl_xor(Gj[rd][p], 1, 64);
      Gj[rd][p] += __shfl_xor(Gj[rd][p], 2, 64);
    }

  // ---- routing: 3 iterations; softmax denom via j-parity partner (xor 4)
  float lgt[5][4], cf[5][4];
#pragma unroll
  for (int rd = 0; rd < 5; ++rd)
#pragma unroll
    for (int aa = 0; aa < 4; ++aa) lgt[rd][aa] = 0.f;

#pragma unroll
  for (int it = 0; it < 3; ++it) {
    float ev[5][4];
    float Sp[4] = {0.f, 0.f, 0.f, 0.f};
#pragma unroll
    for (int rd = 0; rd < 5; ++rd)
#pragma unroll
      for (int aa = 0; aa < 4; ++aa) {
        ev[rd][aa] = __expf(lgt[rd][aa]);
        Sp[aa] += ev[rd][aa];
      }
#pragma unroll
    for (int aa = 0; aa < 4; ++aa) Sp[aa] += __shfl_xor(Sp[aa], 4, 64);
#pragma unroll
    for (int rd = 0; rd < 5; ++rd) {
      float c0 = ev[rd][0] / Sp[0], c1 = ev[rd][1] / Sp[1];
      float c2 = ev[rd][2] / Sp[2], c3 = ev[rd][3] / Sp[3];
      float t0 = c0 * Gj[rd][0] + c1 * Gj[rd][1] + c2 * Gj[rd][2] + c3 * Gj[rd][3];
      float t1 = c0 * Gj[rd][1] + c1 * Gj[rd][4] + c2 * Gj[rd][5] + c3 * Gj[rd][6];
      float t2 = c0 * Gj[rd][2] + c1 * Gj[rd][5] + c2 * Gj[rd][7] + c3 * Gj[rd][8];
      float t3 = c0 * Gj[rd][3] + c1 * Gj[rd][6] + c2 * Gj[rd][8] + c3 * Gj[rd][9];
      float sq = c0 * t0 + c1 * t1 + c2 * t2 + c3 * t3;
      float scale = sq / ((1.f + sq) * sqrtf(sq + 1e-8f));
      if (it < 2) {
        lgt[rd][0] += scale * t0;
        lgt[rd][1] += scale * t1;
        lgt[rd][2] += scale * t2;
        lgt[rd][3] += scale * t3;
      } else {
        cf[rd][0] = scale * c0;
        cf[rd][1] = scale * c1;
        cf[rd][2] = scale * c2;
        cf[rd][3] = scale * c3;
      }
    }
  }

  // ---- v pass: re-read UH (L2/L3-hot), combine, store f32
#pragma unroll
  for (int rd = 0; rd < 5; ++rd) {
    const int nt = 2 * (2 * rd + gjl) + ihh;
    const int j  = 2 * rd + gjl;
    float vv[8];
#pragma unroll
    for (int e = 0; e < 8; ++e) vv[e] = 0.f;
#pragma unroll
    for (int aa = 0; aa < 4; ++aa) {
      f16x8 v = *(const f16x8*)(UH + base0 + (size_t)aa * 5120 + nt * 256);
#pragma unroll
      for (int e = 0; e < 8; ++e) vv[e] += cf[rd][aa] * (float)v[e];
    }
    float* po = out + (size_t)s * 320 + j * 32 + gih * 8;
    f32x4 v0 = {vv[0], vv[1], vv[2], vv[3]};
    f32x4 v1 = {vv[4], vv[5], vv[6], vv[7]};
    *(f32x4*)po       = v0;
    *(f32x4*)(po + 4) = v1;
  }
}

extern "C" void kernel_launch(void* const* d_in, const int* in_sizes, int n_in,
                              void* d_out, int out_size, void* d_ws, size_t ws_size,
                              hipStream_t stream) {
  const float* x  = (const float*)d_in[0];
  const float* W1 = (const float*)d_in[1];
  const float* b1 = (const float*)d_in[2];
  const float* W2 = (const float*)d_in[3];
  const float* b2 = (const float*)d_in[4];
  const float* W  = (const float*)d_in[5];

  unsigned short* wsb = (unsigned short*)d_ws;
  unsigned short* Wfh = wsb;                 // 204800 (frag layout)
  unsigned short* Wfl = wsb + 204800;        // 204800
  unsigned short* W2h = wsb + 409600;        // 16384
  unsigned short* W2l = wsb + 425984;        // 16384
  unsigned short* Wfb = wsb + 442368;        // 81920 (frag layout)
  unsigned int*   H   = (unsigned int*)(wsb + 606208);        // 8,388,608 u32
  _Float16*       UH  = (_Float16*)(H + 8388608);             // 41,943,040 fp16
  float* out = (float*)d_out;

  kprep<<<800, 256, 0, stream>>>(W1, W2, W, Wfh, Wfl, W2h, W2l, Wfb);
  kA<<<512, 512, 0, stream>>>(x, b1, Wfh, Wfl, H);
  kB1<<<2048, 256, 0, stream>>>(H, b2, W2h, W2l, Wfb, UH);
  kB2<<<1024, 256, 0, stream>>>(UH, out);
}

// Round 17
// 139.799 us; speedup vs baseline: 1.1712x; 1.1712x over previous
//
#include <hip/hip_runtime.h>

typedef __bf16 bf16_t;
typedef bf16_t bf16x8 __attribute__((ext_vector_type(8)));
typedef unsigned short u16x8 __attribute__((ext_vector_type(8)));
typedef float f32x4 __attribute__((ext_vector_type(4)));
typedef _Float16 f16x8 __attribute__((ext_vector_type(8)));

union BF8 { u16x8 u; bf16x8 b; };

__device__ __forceinline__ unsigned short f2bf(float f) {
  unsigned int u = __float_as_uint(f);
  unsigned int r = (u + 0x7FFFu + ((u >> 16) & 1u)) >> 16;
  return (unsigned short)r;
}
__device__ __forceinline__ float bf2f(unsigned short s) {
  return __uint_as_float(((unsigned int)s) << 16);
}

// ---------------- prep: weights -> MFMA-frag-ready bf16 layouts --------------
__global__ __launch_bounds__(256) void kprep(const float* __restrict__ W1,
                                             const float* __restrict__ W2,
                                             const float* __restrict__ W,
                                             unsigned short* __restrict__ Wfh,
                                             unsigned short* __restrict__ Wfl,
                                             unsigned short* __restrict__ W2h,
                                             unsigned short* __restrict__ W2l,
                                             unsigned short* __restrict__ Wfb) {
  int idx = blockIdx.x * 256 + threadIdx.x;
  if (idx < 204800) {
    int e = idx & 7, lane = (idx >> 3) & 63, nt = (idx >> 9) & 15, ks = idx >> 13;
    int k = ks * 32 + (lane >> 4) * 8 + e;
    int col = nt * 16 + (lane & 15);
    int a = col >> 6, o = col & 63;
    float v = (k < 784) ? W1[(a * 784 + k) * 64 + o] : 0.f;
    unsigned short hi = f2bf(v);
    Wfh[idx] = hi;
    Wfl[idx] = f2bf(v - bf2f(hi));
  }
  if (idx < 16384) {
    int a = idx >> 12, o = (idx >> 6) & 63, k = idx & 63;
    float v = W2[(a * 64 + k) * 64 + o];
    unsigned short hi = f2bf(v);
    W2h[idx] = hi;
    W2l[idx] = f2bf(v - bf2f(hi));
  }
  if (idx < 81920) {
    int e = idx & 7;
    int t = idx >> 3;
    int lane = t & 63; t >>= 6;
    int kc = t & 1;   t >>= 1;
    int nt = t % 20;
    int a  = t / 20;
    int row = nt * 16 + (lane & 15);
    int kk  = kc * 32 + (lane >> 4) * 8 + e;
    Wfb[idx] = f2bf(W[(a * 320 + row) * 64 + kk]);
  }
}

// ---------------- kA: h = relu(x@W1 + b1), split-bf16, -> packed u32 ---------
// (unchanged from R9) 512 threads, BM=64, x double-buffered, W frags direct.
__global__ __launch_bounds__(512, 4) void kA(const float* __restrict__ x,
                                             const float* __restrict__ b1,
                                             const unsigned short* __restrict__ Wfh,
                                             const unsigned short* __restrict__ Wfl,
                                             unsigned int* __restrict__ H) {
  __shared__ unsigned short xsh[2][64 * 40];
  __shared__ unsigned short xsl[2][64 * 40];
  __shared__ float b1s[256];
  const int tid = threadIdx.x;
  const int w   = tid >> 6;
  const int l   = tid & 63;
  const int l15 = l & 15;
  const int lg4 = l >> 4;
  const int k8  = lg4 * 8;
  const int b0  = blockIdx.x * 64;

  if (tid < 256) b1s[tid] = b1[tid];

  const f32x4 fz = {0.f, 0.f, 0.f, 0.f};
  f32x4 acc[4][2];
#pragma unroll
  for (int mt = 0; mt < 4; ++mt)
#pragma unroll
    for (int n = 0; n < 2; ++n) acc[mt][n] = fz;

  const int srow = tid >> 3;
  const int skq  = (tid & 7) * 4;
  const float* xrow = x + (size_t)(b0 + srow) * 784;

  {
    f32x4 xv = fz;
    if (skq < 784) xv = *(const f32x4*)(xrow + skq);
    unsigned int ph[2], pl[2];
#pragma unroll
    for (int j = 0; j < 2; ++j) {
      unsigned short h0 = f2bf(xv[2 * j]), h1 = f2bf(xv[2 * j + 1]);
      unsigned short s0 = f2bf(xv[2 * j] - bf2f(h0));
      unsigned short s1 = f2bf(xv[2 * j + 1] - bf2f(h1));
      ph[j] = (unsigned int)h0 | ((unsigned int)h1 << 16);
      pl[j] = (unsigned int)s0 | ((unsigned int)s1 << 16);
    }
    *(uint2*)&xsh[0][srow * 40 + skq] = *(uint2*)ph;
    *(uint2*)&xsl[0][srow * 40 + skq] = *(uint2*)pl;
  }

  for (int ks = 0; ks < 25; ++ks) {
    const int cur = ks & 1;
    f32x4 xn = fz;
    if (ks < 24) {
      int kf = (ks + 1) * 32 + skq;
      if (kf < 784) xn = *(const f32x4*)(xrow + kf);
    }
    __syncthreads();

    const int nt0 = w * 2;
    bf16x8 bh0 = *(const bf16x8*)(Wfh + ((size_t)(ks * 16 + nt0) * 64 + l) * 8);
    bf16x8 bl0 = *(const bf16x8*)(Wfl + ((size_t)(ks * 16 + nt0) * 64 + l) * 8);
    bf16x8 bh1 = *(const bf16x8*)(Wfh + ((size_t)(ks * 16 + nt0 + 1) * 64 + l) * 8);
    bf16x8 bl1 = *(const bf16x8*)(Wfl + ((size_t)(ks * 16 + nt0 + 1) * 64 + l) * 8);

    bf16x8 ah[4], al[4];
#pragma unroll
    for (int mt = 0; mt < 4; ++mt) {
      ah[mt] = *(const bf16x8*)&xsh[cur][(mt * 16 + l15) * 40 + k8];
      al[mt] = *(const bf16x8*)&xsl[cur][(mt * 16 + l15) * 40 + k8];
    }

#pragma unroll
    for (int mt = 0; mt < 4; ++mt) {
      acc[mt][0] = __builtin_amdgcn_mfma_f32_16x16x32_bf16(ah[mt], bh0, acc[mt][0], 0, 0, 0);
      acc[mt][0] = __builtin_amdgcn_mfma_f32_16x16x32_bf16(al[mt], bh0, acc[mt][0], 0, 0, 0);
      acc[mt][0] = __builtin_amdgcn_mfma_f32_16x16x32_bf16(ah[mt], bl0, acc[mt][0], 0, 0, 0);
      acc[mt][1] = __builtin_amdgcn_mfma_f32_16x16x32_bf16(ah[mt], bh1, acc[mt][1], 0, 0, 0);
      acc[mt][1] = __builtin_amdgcn_mfma_f32_16x16x32_bf16(al[mt], bh1, acc[mt][1], 0, 0, 0);
      acc[mt][1] = __builtin_amdgcn_mfma_f32_16x16x32_bf16(ah[mt], bl1, acc[mt][1], 0, 0, 0);
    }

    if (ks < 24) {
      unsigned int ph[2], pl[2];
#pragma unroll
      for (int j = 0; j < 2; ++j) {
        unsigned short h0 = f2bf(xn[2 * j]), h1 = f2bf(xn[2 * j + 1]);
        unsigned short s0 = f2bf(xn[2 * j] - bf2f(h0));
        unsigned short s1 = f2bf(xn[2 * j + 1] - bf2f(h1));
        ph[j] = (unsigned int)h0 | ((unsigned int)h1 << 16);
        pl[j] = (unsigned int)s0 | ((unsigned int)s1 << 16);
      }
      *(uint2*)&xsh[cur ^ 1][srow * 40 + skq] = *(uint2*)ph;
      *(uint2*)&xsl[cur ^ 1][srow * 40 + skq] = *(uint2*)pl;
    }
  }

#pragma unroll
  for (int mt = 0; mt < 4; ++mt)
#pragma unroll
    for (int n = 0; n < 2; ++n) {
      int col = (w * 2 + n) * 16 + l15;
      float bb = b1s[col];
#pragma unroll
      for (int r = 0; r < 4; ++r) {
        int row = b0 + mt * 16 + lg4 * 4 + r;
        float v = acc[mt][n][r] + bb;
        v = v > 0.f ? v : 0.f;
        unsigned short hi = f2bf(v);
        unsigned short lo = f2bf(v - bf2f(hi));
        H[(size_t)row * 256 + col] = (unsigned int)hi | ((unsigned int)lo << 16);
      }
    }
}

// ---------------- kB1: GEMM2 + squash + u_hat -> UH (fp16, dump layout) ------
// 16 samples/block (grid 2048), R9's proven phases 1-2; u_hat computed one
// nt at a time (small regs), stored as UH[blk][a][nt][lg4][r][l15] fp16.
__global__ __launch_bounds__(256, 4) void kB1(const unsigned int* __restrict__ H,
                                              const float* __restrict__ b2,
                                              const unsigned short* __restrict__ W2h,
                                              const unsigned short* __restrict__ W2l,
                                              const unsigned short* __restrict__ Wfb,
                                              _Float16* __restrict__ UH) {
  __shared__ float smem[4352];  // u_scr only (R9 layout, stride 68)
  const int tid = threadIdx.x;
  const int a   = tid >> 6;   // wave = agent
  const int l   = tid & 63;
  const int l15 = l & 15;
  const int lg4 = l >> 4;
  const int k8  = lg4 * 8;
  const int b0  = blockIdx.x * 16;
  const f32x4 fz = {0.f, 0.f, 0.f, 0.f};

  // ---- phase 1: GEMM2 (split-bf16) + b2 + squash -> u (f32 in u_scr)
  bf16x8 hh[2], hl[2];
#pragma unroll
  for (int kc = 0; kc < 2; ++kc) {
    const uint4* hp = (const uint4*)(H + (size_t)(b0 + l15) * 256 + a * 64 + kc * 32 + k8);
    uint4 q0 = hp[0], q1 = hp[1];
    unsigned int pw[8] = {q0.x, q0.y, q0.z, q0.w, q1.x, q1.y, q1.z, q1.w};
    BF8 vh, vl;
#pragma unroll
    for (int j = 0; j < 8; ++j) {
      vh.u[j] = (unsigned short)(pw[j] & 0xFFFFu);
      vl.u[j] = (unsigned short)(pw[j] >> 16);
    }
    hh[kc] = vh.b;
    hl[kc] = vl.b;
  }
  f32x4 a2[4];
#pragma unroll
  for (int ot = 0; ot < 4; ++ot) a2[ot] = fz;
#pragma unroll
  for (int ot = 0; ot < 4; ++ot)
#pragma unroll
    for (int kc = 0; kc < 2; ++kc) {
      bf16x8 bh = *(const bf16x8*)(W2h + ((a * 64 + ot * 16 + l15) * 64 + kc * 32 + k8));
      bf16x8 bl = *(const bf16x8*)(W2l + ((a * 64 + ot * 16 + l15) * 64 + kc * 32 + k8));
      a2[ot] = __builtin_amdgcn_mfma_f32_16x16x32_bf16(hh[kc], bh, a2[ot], 0, 0, 0);
      a2[ot] = __builtin_amdgcn_mfma_f32_16x16x32_bf16(hl[kc], bh, a2[ot], 0, 0, 0);
      a2[ot] = __builtin_amdgcn_mfma_f32_16x16x32_bf16(hh[kc], bl, a2[ot], 0, 0, 0);
    }
  float b2v[4];
#pragma unroll
  for (int ot = 0; ot < 4; ++ot) b2v[ot] = b2[a * 64 + ot * 16 + l15];
#pragma unroll
  for (int r = 0; r < 4; ++r) {
    float up[4];
    float sq = 0.f;
#pragma unroll
    for (int ot = 0; ot < 4; ++ot) {
      float v = a2[ot][r] + b2v[ot];
      up[ot] = v;
      sq += v * v;
    }
    sq += __shfl_xor(sq, 1, 64);
    sq += __shfl_xor(sq, 2, 64);
    sq += __shfl_xor(sq, 4, 64);
    sq += __shfl_xor(sq, 8, 64);
    float scale = sq / ((1.f + sq) * sqrtf(sq + 1e-8f));
#pragma unroll
    for (int ot = 0; ot < 4; ++ot)
      smem[a * 1088 + (lg4 * 4 + r) * 68 + ot * 16 + l15] = scale * up[ot];
  }
  __syncthreads();

  // ---- phase 2: u A-frags (transpose read, split hi/lo)
  bf16x8 uah[2], ual[2];
#pragma unroll
  for (int kc = 0; kc < 2; ++kc) {
    float4 f0 = *(const float4*)&smem[a * 1088 + l15 * 68 + kc * 32 + k8];
    float4 f1 = *(const float4*)&smem[a * 1088 + l15 * 68 + kc * 32 + k8 + 4];
    float vv[8] = {f0.x, f0.y, f0.z, f0.w, f1.x, f1.y, f1.z, f1.w};
    BF8 vh, vl;
#pragma unroll
    for (int j = 0; j < 8; ++j) {
      unsigned short hi = f2bf(vv[j]);
      vh.u[j] = hi;
      vl.u[j] = f2bf(vv[j] - bf2f(hi));
    }
    uah[kc] = vh.b;
    ual[kc] = vl.b;
  }

  // ---- phase 3: u_hat MFMA one nt at a time -> UH fp16 (dump layout)
#pragma unroll
  for (int nt = 0; nt < 20; ++nt) {
    f32x4 au = fz;
#pragma unroll
    for (int kc = 0; kc < 2; ++kc) {
      bf16x8 bh = *(const bf16x8*)(Wfb + ((size_t)((a * 20 + nt) * 2 + kc) * 64 + l) * 8);
      au = __builtin_amdgcn_mfma_f32_16x16x32_bf16(uah[kc], bh, au, 0, 0, 0);
      au = __builtin_amdgcn_mfma_f32_16x16x32_bf16(ual[kc], bh, au, 0, 0, 0);
    }
    size_t base = ((((size_t)blockIdx.x * 4 + a) * 20 + nt) * 4 + lg4) * 4;
#pragma unroll
    for (int r = 0; r < 4; ++r)
      UH[(base + r) * 16 + l15] = (_Float16)au[r];
  }
}

// ---------------- kB2: Gram + routing + v from UH (no LDS, no barriers) ------
// 8 threads/sample: (gjl = j parity, gih = i quarter). 32 samples/block.
// R17: launch_bounds (256,3) -- the (256,4) 128-reg cap forced accumulator
// spill (VGPR=64, 109MB scratch writes). ev[] recomputed, not stored.
__global__ __launch_bounds__(256, 3) void kB2(const _Float16* __restrict__ UH,
                                              float* __restrict__ out) {
  const int tid  = threadIdx.x;
  const int gjl  = (tid >> 2) & 1;
  const int gih  = tid & 3;
  const int s    = blockIdx.x * 32 + (tid >> 3);
  const int blk  = s >> 4, l4 = (s >> 2) & 3, rr = s & 3;
  const size_t base0 = (size_t)blk * 20480 + l4 * 64 + rr * 16 + (gih & 1) * 8;
  const int ihh  = gih >> 1;

  float Gj[5][10];
#pragma unroll
  for (int rd = 0; rd < 5; ++rd)
#pragma unroll
    for (int p = 0; p < 10; ++p) Gj[rd][p] = 0.f;

  // ---- Gram pass: 8 i-values per thread per (rd, aa)
#pragma unroll
  for (int rd = 0; rd < 5; ++rd) {
    const int nt = 2 * (2 * rd + gjl) + ihh;
    float f[4][8];
#pragma unroll
    for (int aa = 0; aa < 4; ++aa) {
      f16x8 v = *(const f16x8*)(UH + base0 + (size_t)aa * 5120 + nt * 256);
#pragma unroll
      for (int e = 0; e < 8; ++e) f[aa][e] = (float)v[e];
    }
#pragma unroll
    for (int e = 0; e < 8; ++e) {
      float v0 = f[0][e], v1 = f[1][e], v2 = f[2][e], v3 = f[3][e];
      Gj[rd][0] += v0 * v0; Gj[rd][1] += v0 * v1; Gj[rd][2] += v0 * v2; Gj[rd][3] += v0 * v3;
      Gj[rd][4] += v1 * v1; Gj[rd][5] += v1 * v2; Gj[rd][6] += v1 * v3;
      Gj[rd][7] += v2 * v2; Gj[rd][8] += v2 * v3;
      Gj[rd][9] += v3 * v3;
    }
  }
  // combine i-quarters (lanes xor 1, 2 within the 4-lane gih group)
#pragma unroll
  for (int rd = 0; rd < 5; ++rd)
#pragma unroll
    for (int p = 0; p < 10; ++p) {
      Gj[rd][p] += __shfl_xor(Gj[rd][p], 1, 64);
      Gj[rd][p] += __shfl_xor(Gj[rd][p], 2, 64);
    }

  // ---- routing: 3 iterations; softmax denom via j-parity partner (xor 4)
  float lgt[5][4], cf[5][4];
#pragma unroll
  for (int rd = 0; rd < 5; ++rd)
#pragma unroll
    for (int aa = 0; aa < 4; ++aa) lgt[rd][aa] = 0.f;

#pragma unroll
  for (int it = 0; it < 3; ++it) {
    float Sp[4] = {0.f, 0.f, 0.f, 0.f};
#pragma unroll
    for (int rd = 0; rd < 5; ++rd)
#pragma unroll
      for (int aa = 0; aa < 4; ++aa) Sp[aa] += __expf(lgt[rd][aa]);
#pragma unroll
    for (int aa = 0; aa < 4; ++aa) Sp[aa] += __shfl_xor(Sp[aa], 4, 64);
#pragma unroll
    for (int rd = 0; rd < 5; ++rd) {
      float c0 = __expf(lgt[rd][0]) / Sp[0], c1 = __expf(lgt[rd][1]) / Sp[1];
      float c2 = __expf(lgt[rd][2]) / Sp[2], c3 = __expf(lgt[rd][3]) / Sp[3];
      float t0 = c0 * Gj[rd][0] + c1 * Gj[rd][1] + c2 * Gj[rd][2] + c3 * Gj[rd][3];
      float t1 = c0 * Gj[rd][1] + c1 * Gj[rd][4] + c2 * Gj[rd][5] + c3 * Gj[rd][6];
      float t2 = c0 * Gj[rd][2] + c1 * Gj[rd][5] + c2 * Gj[rd][7] + c3 * Gj[rd][8];
      float t3 = c0 * Gj[rd][3] + c1 * Gj[rd][6] + c2 * Gj[rd][8] + c3 * Gj[rd][9];
      float sq = c0 * t0 + c1 * t1 + c2 * t2 + c3 * t3;
      float scale = sq / ((1.f + sq) * sqrtf(sq + 1e-8f));
      if (it < 2) {
        lgt[rd][0] += scale * t0;
        lgt[rd][1] += scale * t1;
        lgt[rd][2] += scale * t2;
        lgt[rd][3] += scale * t3;
      } else {
        cf[rd][0] = scale * c0;
        cf[rd][1] = scale * c1;
        cf[rd][2] = scale * c2;
        cf[rd][3] = scale * c3;
      }
    }
  }

  // ---- v pass: re-read UH (L2/L3-hot), combine, store f32
#pragma unroll
  for (int rd = 0; rd < 5; ++rd) {
    const int nt = 2 * (2 * rd + gjl) + ihh;
    const int j  = 2 * rd + gjl;
    float vv[8];
#pragma unroll
    for (int e = 0; e < 8; ++e) vv[e] = 0.f;
#pragma unroll
    for (int aa = 0; aa < 4; ++aa) {
      f16x8 v = *(const f16x8*)(UH + base0 + (size_t)aa * 5120 + nt * 256);
#pragma unroll
      for (int e = 0; e < 8; ++e) vv[e] += cf[rd][aa] * (float)v[e];
    }
    float* po = out + (size_t)s * 320 + j * 32 + gih * 8;
    f32x4 v0 = {vv[0], vv[1], vv[2], vv[3]};
    f32x4 v1 = {vv[4], vv[5], vv[6], vv[7]};
    *(f32x4*)po       = v0;
    *(f32x4*)(po + 4) = v1;
  }
}

extern "C" void kernel_launch(void* const* d_in, const int* in_sizes, int n_in,
                              void* d_out, int out_size, void* d_ws, size_t ws_size,
                              hipStream_t stream) {
  const float* x  = (const float*)d_in[0];
  const float* W1 = (const float*)d_in[1];
  const float* b1 = (const float*)d_in[2];
  const float* W2 = (const float*)d_in[3];
  const float* b2 = (const float*)d_in[4];
  const float* W  = (const float*)d_in[5];

  unsigned short* wsb = (unsigned short*)d_ws;
  unsigned short* Wfh = wsb;                 // 204800 (frag layout)
  unsigned short* Wfl = wsb + 204800;        // 204800
  unsigned short* W2h = wsb + 409600;        // 16384
  unsigned short* W2l = wsb + 425984;        // 16384
  unsigned short* Wfb = wsb + 442368;        // 81920 (frag layout)
  unsigned int*   H   = (unsigned int*)(wsb + 606208);        // 8,388,608 u32
  _Float16*       UH  = (_Float16*)(H + 8388608);             // 41,943,040 fp16
  float* out = (float*)d_out;

  kprep<<<800, 256, 0, stream>>>(W1, W2, W, Wfh, Wfl, W2h, W2l, Wfb);
  kA<<<512, 512, 0, stream>>>(x, b1, Wfh, Wfl, H);
  kB1<<<2048, 256, 0, stream>>>(H, b2, W2h, W2l, Wfb, UH);
  kB2<<<1024, 256, 0, stream>>>(UH, out);
}